// Round 6
// baseline (703.497 us; speedup 1.0000x reference)
//
#include <hip/hip_runtime.h>

typedef unsigned int uint;
typedef unsigned short ushort;
typedef __attribute__((ext_vector_type(8))) short short8;
typedef __attribute__((ext_vector_type(4))) float f32x4;

#define DD 256

__device__ __forceinline__ float b2f(ushort u) {
    return __uint_as_float(((uint)u) << 16);
}
__device__ __forceinline__ ushort f2b(float f) {
    uint u = __float_as_uint(f);
    u += 0x7FFFu + ((u >> 16) & 1u);
    return (ushort)(u >> 16);
}
__device__ __forceinline__ void split2(float x, short& h, short& l) {
    uint u = __float_as_uint(x);
    uint hr = (u + 0x7FFFu + ((u >> 16) & 1u)) & 0xFFFF0000u;
    h = (short)(hr >> 16);
    l = (short)(__float_as_uint(x - __uint_as_float(hr)) >> 16);
}
// 4x4 transpose among lanes differing in bits 0..1 (lane&3 groups), a[i] = M[i][lane&3] -> a[i] = M[lane&3][i]
__device__ __forceinline__ void xpose4(float (&a)[4], int l01) {
    float t[4], n[4];
    #pragma unroll
    for (int i = 0; i < 4; ++i) t[i] = __shfl_xor(a[i], 1, 64);
    #pragma unroll
    for (int i = 0; i < 4; ++i) n[i] = ((i ^ l01) & 1) ? t[i ^ 1] : a[i];
    #pragma unroll
    for (int i = 0; i < 4; ++i) t[i] = __shfl_xor(n[i], 2, 64);
    #pragma unroll
    for (int i = 0; i < 4; ++i) a[i] = ((i ^ l01) & 2) ? t[i ^ 2] : n[i];
}

// ======================= weight pre-split, row-major hi/lo (small path, split3) =======================
struct WPtrs5 { const float* w[5]; };

__global__ __launch_bounds__(256) void wcvt_old(WPtrs5 p, ushort* __restrict__ out)
{
    int idx = blockIdx.x * 256 + threadIdx.x;
    int mat = idx >> 14;
    int off = idx & 16383;
    float4 v = *((const float4*)p.w[mat] + off);
    float xs[4] = {v.x, v.y, v.z, v.w};
    ushort h[4], l[4];
    #pragma unroll
    for (int i = 0; i < 4; ++i) {
        short hh, ll;
        split2(xs[i], hh, ll);
        h[i] = (ushort)hh; l[i] = (ushort)ll;
    }
    *((ushort4*)(out + (size_t)mat * 131072) + off) = make_ushort4(h[0], h[1], h[2], h[3]);
    *((ushort4*)(out + (size_t)mat * 131072 + 65536) + off) = make_ushort4(l[0], l[1], l[2], l[3]);
}

// ======================= weight bf16 round, MFMA-fragment order (big path) =======================
struct WPtrs8 { const float* w[8]; };

__global__ __launch_bounds__(256) void wcvt_frag(WPtrs8 p, ushort* __restrict__ out)
{
    int idx = blockIdx.x * 256 + threadIdx.x;    // short8 index; 8*8*16*64 = 65536 total
    int lane = idx & 63;
    int nt = (idx >> 6) & 15;
    int kc = (idx >> 10) & 7;
    int mat = idx >> 13;
    int n = nt * 16 + (lane & 15);
    int k = kc * 32 + (lane >> 4) * 8;
    const float* src = p.w[mat] + n * DD + k;
    float4 x0 = *(const float4*)src;
    float4 x1 = *(const float4*)(src + 4);
    float xs[8] = {x0.x, x0.y, x0.z, x0.w, x1.x, x1.y, x1.z, x1.w};
    short o8[8];
    #pragma unroll
    for (int i = 0; i < 8; ++i) o8[i] = (short)f2b(xs[i]);
    *(short8*)(out + (size_t)idx * 8) = (short8){o8[0],o8[1],o8[2],o8[3],o8[4],o8[5],o8[6],o8[7]};
}

// ======================= fused multi-mat MFMA GEMM: stage-A once, loop mats =======================
struct GemmFused {
    const float* X;            // raw rows [R][256] fp32
    const float2* stats;       // per-seq (mean, rsig) or nullptr
    const float* gnw; const float* gnb;
    const ushort* W;           // fragment-ordered bf16, mats consecutive (65536 shorts each)
    const float* b0; const float* b1; const float* b2;
    void* o0; void* o1; void* o2;
    int bf16mask;              // per-mat: 1 = ROW-MAJOR bf16 out (via 4x4 transpose), 0 = row-major fp32
    int nmat;
};

__global__ __launch_bounds__(256, 2) void gemm_fused(GemmFused p)
{
    __shared__ __align__(16) ushort As[128][264];
    const int tid = threadIdx.x, w = tid >> 6, lane = tid & 63;
    const int quad = lane >> 4, r16 = lane & 15;
    const long row0 = (long)blockIdx.x * 128;
    const int wrow = (w & 1) * 64, wcol = (w >> 1) * 128;
    const bool gn = (p.stats != nullptr);

    float mu = 0.f, rsg = 1.f;
    if (gn) { float2 st = p.stats[row0 >> 9]; mu = st.x; rsg = st.y; }

    // ---- stage entire A tile to LDS (once) ----
    {
        const int arow = tid >> 1;
        const int kh = (tid & 1) * 128;
        const float* src = p.X + (row0 + arow) * DD + kh;
        #pragma unroll
        for (int i = 0; i < 8; ++i) {
            float4 x0 = *(const float4*)(src + i * 16);
            float4 x1 = *(const float4*)(src + i * 16 + 4);
            float4 x2 = *(const float4*)(src + i * 16 + 8);
            float4 x3 = *(const float4*)(src + i * 16 + 12);
            float xs[16] = {x0.x,x0.y,x0.z,x0.w, x1.x,x1.y,x1.z,x1.w,
                            x2.x,x2.y,x2.z,x2.w, x3.x,x3.y,x3.z,x3.w};
            if (gn) {
                const float* gwp = p.gnw + kh + i * 16;
                const float* gbp = p.gnb + kh + i * 16;
                #pragma unroll
                for (int j = 0; j < 16; ++j)
                    xs[j] = (xs[j] - mu) * rsg * gwp[j] + gbp[j];
            }
            short o16[16];
            #pragma unroll
            for (int j = 0; j < 16; ++j) o16[j] = (short)f2b(xs[j]);
            *(short8*)&As[arow][kh + i * 16]     = (short8){o16[0],o16[1],o16[2],o16[3],o16[4],o16[5],o16[6],o16[7]};
            *(short8*)&As[arow][kh + i * 16 + 8] = (short8){o16[8],o16[9],o16[10],o16[11],o16[12],o16[13],o16[14],o16[15]};
        }
    }
    __syncthreads();     // the ONLY barrier

    const int nt0 = wcol >> 4;
    for (int m = 0; m < p.nmat; ++m) {
        const ushort* Wm = p.W + (size_t)m * 65536;
        const float* bias = (m == 0) ? p.b0 : (m == 1 ? p.b1 : p.b2);
        void* out = (m == 0) ? p.o0 : (m == 1 ? p.o1 : p.o2);
        const int isbf = (p.bf16mask >> m) & 1;

        f32x4 acc[4][8];
        #pragma unroll
        for (int mt = 0; mt < 4; ++mt)
            #pragma unroll
            for (int ct = 0; ct < 8; ++ct)
                acc[mt][ct] = (f32x4){0.f, 0.f, 0.f, 0.f};

        #pragma unroll 2
        for (int kc = 0; kc < 8; ++kc) {
            short8 bfr[8];
            #pragma unroll
            for (int ct = 0; ct < 8; ++ct)
                bfr[ct] = *(const short8*)(Wm + (((kc * 16 + nt0 + ct) << 9) + lane * 8));
            short8 af[4];
            #pragma unroll
            for (int mt = 0; mt < 4; ++mt)
                af[mt] = *(const short8*)&As[wrow + mt * 16 + r16][kc * 32 + quad * 8];
            #pragma unroll
            for (int ct = 0; ct < 8; ++ct)
                #pragma unroll
                for (int mt = 0; mt < 4; ++mt)
                    acc[mt][ct] = __builtin_amdgcn_mfma_f32_16x16x32_bf16(af[mt], bfr[ct], acc[mt][ct], 0, 0, 0);
        }

        if (isbf) {
            // 4x4 transpose -> row-major bf16 ushort4 stores (8B/lane, rows complete quickly)
            ushort* o = (ushort*)out;
            const int l01 = lane & 3;
            const int colb = wcol + (r16 & 12);       // group col base (+ct*16)
            #pragma unroll
            for (int mt = 0; mt < 4; ++mt) {
                const long rb = row0 + wrow + mt * 16 + quad * 4 + l01;   // row after transpose
                #pragma unroll
                for (int ct = 0; ct < 8; ++ct) {
                    const float bv = bias[wcol + ct * 16 + r16];
                    float av[4] = {acc[mt][ct][0] + bv, acc[mt][ct][1] + bv,
                                   acc[mt][ct][2] + bv, acc[mt][ct][3] + bv};
                    xpose4(av, l01);
                    *(ushort4*)&o[rb * DD + colb + ct * 16] =
                        make_ushort4(f2b(av[0]), f2b(av[1]), f2b(av[2]), f2b(av[3]));
                }
            }
        } else {
            float* o = (float*)out;
            #pragma unroll
            for (int ct = 0; ct < 8; ++ct) {
                const int col = wcol + ct * 16 + r16;
                const float bv = bias[col];
                #pragma unroll
                for (int mt = 0; mt < 4; ++mt) {
                    const long rb = row0 + wrow + mt * 16 + quad * 4;
                    f32x4 a = acc[mt][ct];
                    #pragma unroll
                    for (int i = 0; i < 4; ++i) o[(rb + i) * DD + col] = a[i] + bv;
                }
            }
        }
    }
}

// ======================= small MFMA GEMM (128-row global path; split3, proven) =======================
struct GemmPtrs {
    const float* X;
    const ushort* W0; const ushort* W1; const ushort* W2;
    const float* b0; const float* b1; const float* b2;
    void* o0; void* o1; void* o2;
    int bf16mask;
};

__global__ __launch_bounds__(256, 2) void gemm_small(GemmPtrs p)
{
    __shared__ __align__(16) short As[2][128][40];
    __shared__ __align__(16) short Bsm[2][256][40];
    const int tid = threadIdx.x;
    const int w = tid >> 6, lane = tid & 63;
    const int quad = lane >> 4, r16 = lane & 15;
    const long row0 = (long)blockIdx.x * 128;
    const int mat = blockIdx.y;
    const ushort* W = (mat == 0) ? p.W0 : (mat == 1 ? p.W1 : p.W2);
    const float* bias = (mat == 0) ? p.b0 : (mat == 1 ? p.b1 : p.b2);
    void* out = (mat == 0) ? p.o0 : (mat == 1 ? p.o1 : p.o2);
    const int isbf = (p.bf16mask >> mat) & 1;
    const int wrow = (w & 1) * 64;
    const int wcol = (w >> 1) * 128;

    f32x4 acc[4][8];
    #pragma unroll
    for (int rt = 0; rt < 4; ++rt)
        #pragma unroll
        for (int ct = 0; ct < 8; ++ct)
            acc[rt][ct] = (f32x4){0.f, 0.f, 0.f, 0.f};

    const int arow = tid >> 1;
    const int kb = (tid & 1) << 4;
    const float* abase = p.X + (row0 + arow) * DD + kb;
    const short* wb = (const short*)W + tid * DD;

    for (int kc = 0; kc < 8; ++kc) {
        __syncthreads();
        {
            const float* src = abase + kc * 32;
            #pragma unroll
            for (int gx = 0; gx < 2; ++gx) {
                float4 x0 = *(const float4*)(src + gx * 8);
                float4 x1 = *(const float4*)(src + gx * 8 + 4);
                float xs[8] = {x0.x, x0.y, x0.z, x0.w, x1.x, x1.y, x1.z, x1.w};
                short h[8], l[8];
                #pragma unroll
                for (int i = 0; i < 8; ++i) split2(xs[i], h[i], l[i]);
                *(short8*)&As[0][arow][kb + gx * 8] = (short8){h[0],h[1],h[2],h[3],h[4],h[5],h[6],h[7]};
                *(short8*)&As[1][arow][kb + gx * 8] = (short8){l[0],l[1],l[2],l[3],l[4],l[5],l[6],l[7]};
            }
        }
        {
            const short* srcH = wb + kc * 32;
            const short* srcL = srcH + 65536;
            #pragma unroll
            for (int gx = 0; gx < 4; ++gx) {
                *(short8*)&Bsm[0][tid][gx * 8] = *(const short8*)(srcH + gx * 8);
                *(short8*)&Bsm[1][tid][gx * 8] = *(const short8*)(srcL + gx * 8);
            }
        }
        __syncthreads();
        short8 af[4][2];
        #pragma unroll
        for (int rt = 0; rt < 4; ++rt) {
            const int rr = wrow + rt * 16 + r16;
            af[rt][0] = *(const short8*)&As[0][rr][quad * 8];
            af[rt][1] = *(const short8*)&As[1][rr][quad * 8];
        }
        #pragma unroll
        for (int ct = 0; ct < 8; ++ct) {
            const int cc = wcol + ct * 16 + r16;
            short8 bh = *(const short8*)&Bsm[0][cc][quad * 8];
            short8 bl = *(const short8*)&Bsm[1][cc][quad * 8];
            #pragma unroll
            for (int rt = 0; rt < 4; ++rt) {
                acc[rt][ct] = __builtin_amdgcn_mfma_f32_16x16x32_bf16(af[rt][0], bh, acc[rt][ct], 0, 0, 0);
                acc[rt][ct] = __builtin_amdgcn_mfma_f32_16x16x32_bf16(af[rt][0], bl, acc[rt][ct], 0, 0, 0);
                acc[rt][ct] = __builtin_amdgcn_mfma_f32_16x16x32_bf16(af[rt][1], bh, acc[rt][ct], 0, 0, 0);
            }
        }
    }
    #pragma unroll
    for (int ct = 0; ct < 8; ++ct) {
        const int col = wcol + ct * 16 + r16;
        const float bv = bias[col];
        #pragma unroll
        for (int rt = 0; rt < 4; ++rt) {
            const long rb = row0 + wrow + rt * 16 + quad * 4;
            f32x4 a = acc[rt][ct];
            if (isbf) {
                ushort* o = (ushort*)out;
                #pragma unroll
                for (int i = 0; i < 4; ++i) o[(rb + i) * DD + col] = f2b(a[i] + bv);
            } else {
                float* o = (float*)out;
                #pragma unroll
                for (int i = 0; i < 4; ++i) o[(rb + i) * DD + col] = a[i] + bv;
            }
        }
    }
}

// ======================= banded attention: MFMA scores (split-Q) + LDS-S^T + VALU PV =======================
// grid (cseq, 8 row-tiles, 8 heads), 64 threads (one wave). K/V row-major bf16, Q fp32.
__global__ __launch_bounds__(64) void attn_mfma(const float* __restrict__ Q, const ushort* __restrict__ K,
                                                const ushort* __restrict__ V, float* __restrict__ O,
                                                float* __restrict__ part)
{
    __shared__ __align__(16) ushort Kt[96][40];
    __shared__ __align__(16) ushort Vt[96][44];
    __shared__ __align__(16) float  St[96][36];   // S^T[j][i_pass]
    const int lane = threadIdx.x;
    const int quad = lane >> 4, r16 = lane & 15;
    const int t0 = blockIdx.y * 64;
    const int h = blockIdx.z;
    const long sbase = (long)blockIdx.x * 512;
    const int ktrows = (512 - t0) < 96 ? (512 - t0) : 96;

    // ---- stage K/V (zero-fill beyond ktrows to avoid NaN poison) ----
    #pragma unroll
    for (int it = 0; it < 12; ++it) {
        int u = lane + it * 64;                 // 768 units = 96 rows x 8 dim-quads
        int r = u >> 3, c4 = (u & 7) << 2;
        ushort4 kv = make_ushort4(0, 0, 0, 0), vv = make_ushort4(0, 0, 0, 0);
        if (r < ktrows) {
            long g = (sbase + t0 + r) * DD + h * 32 + c4;
            kv = *(const ushort4*)&K[g];
            vv = *(const ushort4*)&V[g];
        }
        *(ushort4*)&Kt[r][c4] = kv;
        *(ushort4*)&Vt[r][c4] = vv;
    }
    __syncthreads();

    float sm = 0.f, ssum = 0.f;

    #pragma unroll
    for (int p = 0; p < 2; ++p) {
        // ---- scores for local rows p*32 .. p*32+31 (2 row-tiles x 3 col-tiles) ----
        #pragma unroll
        for (int mt = 0; mt < 2; ++mt) {
            const int mta = p * 2 + mt;          // absolute 16-row tile (0..3)
            const int i0 = mta * 16;
            // A-frag (hi/lo split) from global fp32 Q
            const float* qp = &Q[(sbase + t0 + i0 + r16) * DD + h * 32 + quad * 8];
            float4 q0 = *(const float4*)qp;
            float4 q1 = *(const float4*)(qp + 4);
            float qs[8] = {q0.x, q0.y, q0.z, q0.w, q1.x, q1.y, q1.z, q1.w};
            short qh[8], ql[8];
            #pragma unroll
            for (int j = 0; j < 8; ++j) split2(qs[j], qh[j], ql[j]);
            short8 ah = {qh[0],qh[1],qh[2],qh[3],qh[4],qh[5],qh[6],qh[7]};
            short8 al = {ql[0],ql[1],ql[2],ql[3],ql[4],ql[5],ql[6],ql[7]};
            #pragma unroll
            for (int dnt = 0; dnt < 3; ++dnt) {
                const int nt = mta + dnt;        // <= 5
                short8 kb = *(const short8*)&Kt[nt * 16 + r16][quad * 8];
                f32x4 acc = (f32x4){0.f, 0.f, 0.f, 0.f};
                acc = __builtin_amdgcn_mfma_f32_16x16x32_bf16(ah, kb, acc, 0, 0, 0);
                acc = __builtin_amdgcn_mfma_f32_16x16x32_bf16(al, kb, acc, 0, 0, 0);
                const int j_loc = nt * 16 + r16;
                const int ib = i0 + quad * 4;
                f32x4 sv;
                #pragma unroll
                for (int e = 0; e < 4; ++e) {
                    int delta = j_loc - (ib + e);
                    bool valid = (delta >= 0) && (delta < 32) && (j_loc < ktrows);
                    sv[e] = valid ? acc[e] * __expf(-(float)delta) : 0.f;   // select, not mul (NaN-safe)
                }
                *(f32x4*)&St[j_loc][mt * 16 + quad * 4] = sv;
            }
        }
        __syncthreads();
        // ---- PV: rows p*32..p*32+31, lane = (rI 0..15, q4 0..3) ----
        const int rI = lane >> 2, q4 = lane & 3;
        #pragma unroll
        for (int sp = 0; sp < 2; ++sp) {
            const int ip = sp * 16 + rI;         // i within pass (0..31)
            const int il = p * 32 + ip;          // local row
            float oa[8] = {0.f,0.f,0.f,0.f,0.f,0.f,0.f,0.f};
            #pragma unroll 4
            for (int dl = 0; dl < 32; ++dl) {
                const int j = il + dl;           // <= 94
                float s = St[j][ip];             // broadcast over q4, conflict-free (5*rI banks)
                ushort4 v0 = *(const ushort4*)&Vt[j][q4 * 8];
                ushort4 v1 = *(const ushort4*)&Vt[j][q4 * 8 + 4];
                oa[0] += s * b2f(v0.x); oa[1] += s * b2f(v0.y);
                oa[2] += s * b2f(v0.z); oa[3] += s * b2f(v0.w);
                oa[4] += s * b2f(v1.x); oa[5] += s * b2f(v1.y);
                oa[6] += s * b2f(v1.z); oa[7] += s * b2f(v1.w);
            }
            float* op = &O[(sbase + t0 + il) * DD + h * 32 + q4 * 8];
            *(float4*)op       = make_float4(oa[0], oa[1], oa[2], oa[3]);
            *(float4*)(op + 4) = make_float4(oa[4], oa[5], oa[6], oa[7]);
            #pragma unroll
            for (int k = 0; k < 8; ++k) { sm += oa[k]; ssum += oa[k] * oa[k]; }
        }
        __syncthreads();
    }
    // ---- fused GN partial stats ----
    #pragma unroll
    for (int off = 32; off > 0; off >>= 1) {
        sm   += __shfl_down(sm, off, 64);
        ssum += __shfl_down(ssum, off, 64);
    }
    if (lane == 0) {
        atomicAdd(&part[2 * blockIdx.x], sm);
        atomicAdd(&part[2 * blockIdx.x + 1], ssum);
    }
}

// ======================= small dense attention (N=32), row-major bf16 K/V =======================
__global__ __launch_bounds__(64) void small_attn(const float* __restrict__ Q, const ushort* __restrict__ K,
                                                 const ushort* __restrict__ V, float* __restrict__ O)
{
    int b = blockIdx.x >> 3, h = blockIdx.x & 7;
    int i = threadIdx.x;
    if (i >= 32) return;
    long base = (long)b * 32 * DD + h * 32;
    float qr[32], o[32];
    #pragma unroll
    for (int d4 = 0; d4 < 8; ++d4) {
        float4 t = *(const float4*)&Q[base + (long)i * DD + d4 * 4];
        qr[d4*4+0] = t.x; qr[d4*4+1] = t.y; qr[d4*4+2] = t.z; qr[d4*4+3] = t.w;
    }
    #pragma unroll
    for (int d = 0; d < 32; ++d) o[d] = 0.f;
    for (int j = i; j < 32; ++j) {
        float s = 0.f;
        #pragma unroll
        for (int d4 = 0; d4 < 8; ++d4) {
            ushort4 kv = *(const ushort4*)&K[base + (long)j * DD + d4 * 4];
            s += qr[d4*4+0]*b2f(kv.x) + qr[d4*4+1]*b2f(kv.y) + qr[d4*4+2]*b2f(kv.z) + qr[d4*4+3]*b2f(kv.w);
        }
        s *= __expf(-(float)(j - i));
        #pragma unroll
        for (int d4 = 0; d4 < 8; ++d4) {
            ushort4 vv = *(const ushort4*)&V[base + (long)j * DD + d4 * 4];
            o[d4*4+0] += s*b2f(vv.x); o[d4*4+1] += s*b2f(vv.y); o[d4*4+2] += s*b2f(vv.z); o[d4*4+3] += s*b2f(vv.w);
        }
    }
    #pragma unroll
    for (int d4 = 0; d4 < 8; ++d4)
        *(float4*)&O[base + (long)i * DD + d4 * 4] = make_float4(o[d4*4+0], o[d4*4+1], o[d4*4+2], o[d4*4+3]);
}

// ======================= GN helpers =======================
__global__ __launch_bounds__(256) void gnzero(float* __restrict__ part)
{
    part[threadIdx.x] = 0.f;
}

__global__ __launch_bounds__(256) void gn_stats(const float* __restrict__ buf, float2* __restrict__ part, int rpb)
{
    const int s = blockIdx.x;
    const long base = (long)s * rpb * DD;
    const float4* p = (const float4*)(buf + base);
    const int nf4 = rpb * 64;
    float sm = 0.f, ss = 0.f;
    for (int i = threadIdx.x; i < nf4; i += 256) {
        float4 v = p[i];
        sm += v.x + v.y + v.z + v.w;
        ss += v.x*v.x + v.y*v.y + v.z*v.z + v.w*v.w;
    }
    #pragma unroll
    for (int off = 32; off > 0; off >>= 1) {
        sm += __shfl_down(sm, off, 64);
        ss += __shfl_down(ss, off, 64);
    }
    __shared__ float rs[4], rss[4];
    if ((threadIdx.x & 63) == 0) { rs[threadIdx.x >> 6] = sm; rss[threadIdx.x >> 6] = ss; }
    __syncthreads();
    if (threadIdx.x == 0)
        part[s] = make_float2(rs[0]+rs[1]+rs[2]+rs[3], rss[0]+rss[1]+rss[2]+rss[3]);
}

__global__ __launch_bounds__(256) void gn_final(float* __restrict__ part, float2* __restrict__ stats,
                                                int ng, float invN)
{
    int t = threadIdx.x;
    if (t < ng) {
        float sm = part[2*t], ss = part[2*t+1];
        float mean = sm * invN;
        float var = ss * invN - mean * mean;
        stats[t] = make_float2(mean, rsqrtf(var + 1e-5f));
        part[2*t] = 0.f; part[2*t+1] = 0.f;
    }
}

__global__ __launch_bounds__(256) void gn_apply(float* __restrict__ buf, const float2* __restrict__ stats,
                                                const float* __restrict__ w, const float* __restrict__ b, int shift)
{
    long i = (long)blockIdx.x * 256 + threadIdx.x;
    long e = i * 4;
    int seq = (int)(e >> shift);
    int d0 = (int)(e & 255);
    float2 st = stats[seq];
    float4 v = ((const float4*)buf)[i];
    float4 wv = *(const float4*)&w[d0];
    float4 bv = *(const float4*)&b[d0];
    v.x = (v.x - st.x) * st.y * wv.x + bv.x;
    v.y = (v.y - st.x) * st.y * wv.y + bv.y;
    v.z = (v.z - st.x) * st.y * wv.z + bv.z;
    v.w = (v.w - st.x) * st.y * wv.w + bv.w;
    ((float4*)buf)[i] = v;
}

// ======================= softmax-pool =======================
// big path: row-major bf16 gate pre-activations + raw X + fused GN
__global__ __launch_bounds__(256) void pool_partial_big(const ushort* __restrict__ AW, const ushort* __restrict__ AU,
                                                        const float* __restrict__ X, const float2* __restrict__ stats,
                                                        const float* __restrict__ gnw, const float* __restrict__ gnb,
                                                        const float* __restrict__ g,
                                                        float* __restrict__ part, int rpb)
{
    const int s = blockIdx.x, ch = blockIdx.y, NC = gridDim.y, d = threadIdx.x;
    const long rowbase = ((long)s * NC + ch) * rpb;
    const float g0s = g[0];
    const float2 st = stats[s];
    const float wd = gnw[d], bd = gnb[d];
    float l = 0.f, acc = 0.f;
    for (int j = 0; j < rpb; ++j) {
        long idx = (rowbase + j) * DD + d;
        float aw = b2f(AW[idx]);
        float au = b2f(AU[idx]);
        float x = (X[idx] - st.x) * st.y * wd + bd;
        float a = g0s * tanhf(aw) * (1.f / (1.f + __expf(-au)));
        float e = __expf(a);
        l += e; acc += e * x;
    }
    long pbase = (long)(s * NC + ch) * 512;
    part[pbase + d] = l;
    part[pbase + 256 + d] = acc;
}

__global__ __launch_bounds__(256) void pool_partial_small(const float* __restrict__ AW, const float* __restrict__ AU,
                                                          const float* __restrict__ X, const float* __restrict__ g,
                                                          float* __restrict__ part, int rpb)
{
    const int s = blockIdx.x, d = threadIdx.x;
    const long rowbase = (long)s * rpb;
    const float g0 = g[0];
    float l = 0.f, acc = 0.f;
    for (int j = 0; j < rpb; ++j) {
        long idx = (rowbase + j) * DD + d;
        float a = g0 * tanhf(AW[idx]) * (1.f / (1.f + __expf(-AU[idx])));
        float e = __expf(a);
        l += e; acc += e * X[idx];
    }
    long pbase = (long)s * 512;
    part[pbase + d] = l;
    part[pbase + 256 + d] = acc;
}

__global__ __launch_bounds__(256) void pool_final(const float* __restrict__ part, float* __restrict__ out, int NC)
{
    const int s = blockIdx.x, d = threadIdx.x;
    float l = 0.f, acc = 0.f;
    for (int c = 0; c < NC; ++c) {
        long pbase = (long)(s * NC + c) * 512;
        l += part[pbase + d];
        acc += part[pbase + 256 + d];
    }
    out[(long)s * DD + d] = acc / l;
}

// ======================= BatchNorm + classifier =======================
__global__ __launch_bounds__(256) void bn_cls(const float* __restrict__ emb, const float* __restrict__ bn_w,
                                              const float* __restrict__ bn_b, const float* __restrict__ cls_W,
                                              const float* __restrict__ cls_b, float* __restrict__ out)
{
    int d = threadIdx.x;
    float e0 = emb[d], e1 = emb[256 + d], e2 = emb[512 + d], e3 = emb[768 + d];
    float mu = 0.25f * (e0 + e1 + e2 + e3);
    float v0 = e0 - mu, v1 = e1 - mu, v2 = e2 - mu, v3 = e3 - mu;
    float var = 0.25f * (v0*v0 + v1*v1 + v2*v2 + v3*v3);
    float rs = rsqrtf(var + 1e-5f);
    float w = bn_w[d], bb = bn_b[d];
    float z0 = v0*rs*w + bb, z1 = v1*rs*w + bb, z2 = v2*rs*w + bb, z3 = v3*rs*w + bb;
    float w0 = cls_W[d], w1 = cls_W[256 + d];
    __shared__ float red[8][256];
    red[0][d] = z0*w0; red[1][d] = z0*w1;
    red[2][d] = z1*w0; red[3][d] = z1*w1;
    red[4][d] = z2*w0; red[5][d] = z2*w1;
    red[6][d] = z3*w0; red[7][d] = z3*w1;
    __syncthreads();
    for (int off = 128; off > 0; off >>= 1) {
        if (d < off) {
            #pragma unroll
            for (int m = 0; m < 8; ++m) red[m][d] += red[m][d + off];
        }
        __syncthreads();
    }
    if (d < 8) out[d] = red[d][0] + cls_b[d & 1];
}

// ======================= host =======================
extern "C" void kernel_launch(void* const* d_in, const int* in_sizes, int n_in,
                              void* d_out, int out_size, void* d_ws, size_t ws_size,
                              hipStream_t stream)
{
    (void)in_sizes; (void)n_in; (void)out_size;
#define F(i) ((const float*)d_in[i])
    const float* bags = F(0);

    const size_t smallF = 1600000;
    int nch = 1;
    while (nch < 128) {
        size_t bigF_ = ((size_t)(128 / nch)) * 512 * 256;
        if ((3 * bigF_ + smallF) * 4 <= ws_size) break;
        nch <<= 1;
    }
    const int cseq = 128 / nch;
    const size_t crows = (size_t)cseq * 512;
    const size_t bigF = crows * 256;

    float* Xb  = (float*)d_ws;                 // attn output / gemm input (raw fp32)
    float* Qb  = Xb + bigF;                    // Q fp32
    float* KVb = Xb + 2 * bigF;                // K,V row-major bf16 halves; later AW,AU
    ushort* Kb = (ushort*)KVb;
    ushort* Vb = Kb + crows * 256;
    float* sm = Xb + 3 * bigF;
    ushort* Wbig = (ushort*)sm;                // 8 mats x 65536 shorts (frag order, bf16)
    ushort* Wsm  = Wbig + 8 * 65536;           // 5 mats x 131072 shorts (hi/lo row-major)
    float* after = sm + 262144 + 327680;
    float* local_ = after;                     // 128*256
    float* gq   = local_ + 32768;
    float* gkv  = gq + 32768;
    ushort* gkb = (ushort*)gkv;
    ushort* gvb = gkb + 32768;
    float* go   = gkv + 32768;
    float* AWg  = go + 32768;
    float* AUg  = AWg + 32768;
    float* embb = AUg + 32768;                 // 1024
    float* gnpart = embb + 1024;               // 256 floats
    float2* gnstats = (float2*)(gnpart + 256); // 128 x float2
    float* ppart = gnpart + 512;               // [1024][512] max

    // --- weight conversion ---
    WPtrs8 wb8; const int bigidx[8] = {1, 3, 5, 9, 11, 13, 25, 27};
    for (int i = 0; i < 8; ++i) wb8.w[i] = F(bigidx[i]);
    wcvt_frag<<<256, 256, 0, stream>>>(wb8, Wbig);
    WPtrs5 ws5; const int smidx[5] = {17, 19, 21, 30, 32};
    for (int i = 0; i < 5; ++i) ws5.w[i] = F(smidx[i]);
    wcvt_old<<<320, 256, 0, stream>>>(ws5, Wsm);
    gnzero<<<1, 256, 0, stream>>>(gnpart);

    dim3 blk(256);
    const int gx = (int)(crows / 128);
    const float invBig = 1.f / 131072.f;

    for (int c = 0; c < nch; ++c) {
        const float* xin = bags + (size_t)c * bigF;
        // retention 1 (Q fp32 row-major, K/V row-major bf16)
        GemmFused g1 = {xin, nullptr, nullptr, nullptr, Wbig,
                        F(2), F(4), F(6), Qb, Kb, Vb, 0b110, 3};
        gemm_fused<<<gx, blk, 0, stream>>>(g1);
        attn_mfma<<<dim3(cseq, 8, 8), 64, 0, stream>>>(Qb, Kb, Vb, Xb, gnpart);
        gn_final<<<1, blk, 0, stream>>>(gnpart, gnstats, cseq, invBig);
        // retention 2 (GN of layer1 fused into A-staging)
        GemmFused g2 = {Xb, gnstats, F(7), F(8), Wbig + 3 * 65536,
                        F(10), F(12), F(14), Qb, Kb, Vb, 0b110, 3};
        gemm_fused<<<gx, blk, 0, stream>>>(g2);
        attn_mfma<<<dim3(cseq, 8, 8), 64, 0, stream>>>(Qb, Kb, Vb, Xb, gnpart);
        gn_final<<<1, blk, 0, stream>>>(gnpart, gnstats, cseq, invBig);
        // local pool (GN of layer2 fused; gates out row-major bf16)
        GemmFused gp = {Xb, gnstats, F(15), F(16), Wbig + 6 * 65536,
                        F(26), F(28), nullptr, Kb, Vb, nullptr, 0b11, 2};
        gemm_fused<<<gx, blk, 0, stream>>>(gp);
        pool_partial_big<<<dim3(cseq, 8), blk, 0, stream>>>(Kb, Vb, Xb, gnstats, F(15), F(16), F(29), ppart, 64);
        pool_final<<<cseq, blk, 0, stream>>>(ppart, local_ + (size_t)c * cseq * 256, 8);
    }

    // global retention on local [4 x 32 x 256] = 128 rows
    GemmPtrs gg = {local_, Wsm, Wsm + 131072, Wsm + 2 * 131072,
                   F(18), F(20), F(22), gq, gkb, gvb, 0b110};
    gemm_small<<<dim3(1, 3), blk, 0, stream>>>(gg);
    small_attn<<<32, 64, 0, stream>>>(gq, gkb, gvb, go);
    gn_stats<<<4, blk, 0, stream>>>(go, (float2*)gnpart, 32);
    gn_final<<<1, blk, 0, stream>>>(gnpart, gnstats, 4, 1.f / 8192.f);
    gn_apply<<<32, blk, 0, stream>>>(go, gnstats, F(23), F(24), 13);

    GemmPtrs gpg = {go, Wsm + 3 * 131072, Wsm + 4 * 131072, nullptr,
                    F(31), F(33), nullptr, AWg, AUg, nullptr, 0};
    gemm_small<<<dim3(1, 2), blk, 0, stream>>>(gpg);
    pool_partial_small<<<4, blk, 0, stream>>>(AWg, AUg, go, F(34), ppart, 32);
    pool_final<<<4, blk, 0, stream>>>(ppart, embb, 1);

    bn_cls<<<1, blk, 0, stream>>>(embb, F(35), F(36), F(37), F(38), (float*)d_out);
#undef F
}

// Round 7
// 612.461 us; speedup vs baseline: 1.1486x; 1.1486x over previous
//
#include <hip/hip_runtime.h>

typedef unsigned int uint;
typedef unsigned short ushort;
typedef __attribute__((ext_vector_type(8))) short short8;
typedef __attribute__((ext_vector_type(4))) float f32x4;

#define DD 256

__device__ __forceinline__ float b2f(ushort u) {
    return __uint_as_float(((uint)u) << 16);
}
__device__ __forceinline__ ushort f2b(float f) {
    uint u = __float_as_uint(f);
    u += 0x7FFFu + ((u >> 16) & 1u);
    return (ushort)(u >> 16);
}
__device__ __forceinline__ void split2(float x, short& h, short& l) {
    uint u = __float_as_uint(x);
    uint hr = (u + 0x7FFFu + ((u >> 16) & 1u)) & 0xFFFF0000u;
    h = (short)(hr >> 16);
    l = (short)(__float_as_uint(x - __uint_as_float(hr)) >> 16);
}
// scrambled bf16 layout (big path): element (r, c) of an [R][256] matrix lives at
//   t=r>>7, r7=r&127, w=((r7>>6)&1)|(((c>>7)&1)<<1), mt=(r7>>4)&3, quad=(r7>>2)&3, i=r7&3,
//   ct=(c>>4)&7, r16=c&15
//   addr = t*32768 + w*8192 + (mt*8+ct)*256 + (quad*16+r16)*4 + i
__device__ __forceinline__ size_t scramble4(int g0, int c) {   // i==0 base (rows g0..g0+3)
    int t = g0 >> 7, r7 = g0 & 127;
    int w_ = ((r7 >> 6) & 1) | (((c >> 7) & 1) << 1);
    int mt = (r7 >> 4) & 3, quad = (r7 >> 2) & 3;
    int ct = (c >> 4) & 7, r16 = c & 15;
    return (size_t)t * 32768 + w_ * 8192 + (mt * 8 + ct) * 256 + (quad * 16 + r16) * 4;
}

// ======================= weight pre-split, row-major hi/lo (small path, split3) =======================
struct WPtrs5 { const float* w[5]; };

__global__ __launch_bounds__(256) void wcvt_old(WPtrs5 p, ushort* __restrict__ out)
{
    int idx = blockIdx.x * 256 + threadIdx.x;
    int mat = idx >> 14;
    int off = idx & 16383;
    float4 v = *((const float4*)p.w[mat] + off);
    float xs[4] = {v.x, v.y, v.z, v.w};
    ushort h[4], l[4];
    #pragma unroll
    for (int i = 0; i < 4; ++i) {
        short hh, ll;
        split2(xs[i], hh, ll);
        h[i] = (ushort)hh; l[i] = (ushort)ll;
    }
    *((ushort4*)(out + (size_t)mat * 131072) + off) = make_ushort4(h[0], h[1], h[2], h[3]);
    *((ushort4*)(out + (size_t)mat * 131072 + 65536) + off) = make_ushort4(l[0], l[1], l[2], l[3]);
}

// ======================= weight bf16 round, MFMA-fragment order (big path) =======================
struct WPtrs8 { const float* w[8]; };

__global__ __launch_bounds__(256) void wcvt_frag(WPtrs8 p, ushort* __restrict__ out)
{
    int idx = blockIdx.x * 256 + threadIdx.x;    // short8 index; 8*8*16*64 = 65536 total
    int lane = idx & 63;
    int nt = (idx >> 6) & 15;
    int kc = (idx >> 10) & 7;
    int mat = idx >> 13;
    int n = nt * 16 + (lane & 15);
    int k = kc * 32 + (lane >> 4) * 8;
    const float* src = p.w[mat] + n * DD + k;
    float4 x0 = *(const float4*)src;
    float4 x1 = *(const float4*)(src + 4);
    float xs[8] = {x0.x, x0.y, x0.z, x0.w, x1.x, x1.y, x1.z, x1.w};
    short o8[8];
    #pragma unroll
    for (int i = 0; i < 8; ++i) o8[i] = (short)f2b(xs[i]);
    *(short8*)(out + (size_t)idx * 8) = (short8){o8[0],o8[1],o8[2],o8[3],o8[4],o8[5],o8[6],o8[7]};
}

// ======================= fused multi-mat MFMA GEMM: stage-A once, loop mats =======================
struct GemmFused {
    const float* X;            // raw rows [R][256] fp32
    const float2* stats;       // per-seq (mean, rsig) or nullptr
    const float* gnw; const float* gnb;
    const ushort* W;           // fragment-ordered bf16, mats consecutive (65536 shorts each)
    const float* b0; const float* b1; const float* b2;
    void* o0; void* o1; void* o2;
    int bf16mask;              // per-mat: 1 = scrambled bf16 out, 0 = row-major fp32 out
    int nmat;
};

__global__ __launch_bounds__(256, 2) void gemm_fused(GemmFused p)
{
    __shared__ __align__(16) ushort As[128][264];
    const int tid = threadIdx.x, w = tid >> 6, lane = tid & 63;
    const int quad = lane >> 4, r16 = lane & 15;
    const long row0 = (long)blockIdx.x * 128;
    const int wrow = (w & 1) * 64, wcol = (w >> 1) * 128;
    const bool gn = (p.stats != nullptr);

    float mu = 0.f, rsg = 1.f;
    if (gn) { float2 st = p.stats[row0 >> 9]; mu = st.x; rsg = st.y; }

    // ---- stage entire A tile to LDS (once) ----
    {
        const int arow = tid >> 1;
        const int kh = (tid & 1) * 128;
        const float* src = p.X + (row0 + arow) * DD + kh;
        #pragma unroll
        for (int i = 0; i < 8; ++i) {
            float4 x0 = *(const float4*)(src + i * 16);
            float4 x1 = *(const float4*)(src + i * 16 + 4);
            float4 x2 = *(const float4*)(src + i * 16 + 8);
            float4 x3 = *(const float4*)(src + i * 16 + 12);
            float xs[16] = {x0.x,x0.y,x0.z,x0.w, x1.x,x1.y,x1.z,x1.w,
                            x2.x,x2.y,x2.z,x2.w, x3.x,x3.y,x3.z,x3.w};
            if (gn) {
                const float* gwp = p.gnw + kh + i * 16;
                const float* gbp = p.gnb + kh + i * 16;
                #pragma unroll
                for (int j = 0; j < 16; ++j)
                    xs[j] = (xs[j] - mu) * rsg * gwp[j] + gbp[j];
            }
            short o16[16];
            #pragma unroll
            for (int j = 0; j < 16; ++j) o16[j] = (short)f2b(xs[j]);
            *(short8*)&As[arow][kh + i * 16]     = (short8){o16[0],o16[1],o16[2],o16[3],o16[4],o16[5],o16[6],o16[7]};
            *(short8*)&As[arow][kh + i * 16 + 8] = (short8){o16[8],o16[9],o16[10],o16[11],o16[12],o16[13],o16[14],o16[15]};
        }
    }
    __syncthreads();     // the ONLY barrier

    const int nt0 = wcol >> 4;
    for (int m = 0; m < p.nmat; ++m) {
        const ushort* Wm = p.W + (size_t)m * 65536;
        const float* bias = (m == 0) ? p.b0 : (m == 1 ? p.b1 : p.b2);
        void* out = (m == 0) ? p.o0 : (m == 1 ? p.o1 : p.o2);
        const int isbf = (p.bf16mask >> m) & 1;

        f32x4 acc[4][8];
        #pragma unroll
        for (int mt = 0; mt < 4; ++mt)
            #pragma unroll
            for (int ct = 0; ct < 8; ++ct)
                acc[mt][ct] = (f32x4){0.f, 0.f, 0.f, 0.f};

        #pragma unroll 2
        for (int kc = 0; kc < 8; ++kc) {
            short8 bfr[8];
            #pragma unroll
            for (int ct = 0; ct < 8; ++ct)
                bfr[ct] = *(const short8*)(Wm + (((kc * 16 + nt0 + ct) << 9) + lane * 8));
            short8 af[4];
            #pragma unroll
            for (int mt = 0; mt < 4; ++mt)
                af[mt] = *(const short8*)&As[wrow + mt * 16 + r16][kc * 32 + quad * 8];
            #pragma unroll
            for (int ct = 0; ct < 8; ++ct)
                #pragma unroll
                for (int mt = 0; mt < 4; ++mt)
                    acc[mt][ct] = __builtin_amdgcn_mfma_f32_16x16x32_bf16(af[mt], bfr[ct], acc[mt][ct], 0, 0, 0);
        }

        if (isbf) {
            // scrambled bf16 store: per (mt,ct) one ushort4 per lane, 512B contiguous per instr
            ushort* o = (ushort*)out;
            const size_t base = (size_t)blockIdx.x * 32768 + (size_t)w * 8192 + (size_t)lane * 4;
            #pragma unroll
            for (int ct = 0; ct < 8; ++ct) {
                const float bv = bias[wcol + ct * 16 + r16];
                #pragma unroll
                for (int mt = 0; mt < 4; ++mt) {
                    f32x4 a = acc[mt][ct];
                    *(ushort4*)&o[base + (size_t)(mt * 8 + ct) * 256] =
                        make_ushort4(f2b(a[0]+bv), f2b(a[1]+bv), f2b(a[2]+bv), f2b(a[3]+bv));
                }
            }
        } else {
            float* o = (float*)out;
            #pragma unroll
            for (int ct = 0; ct < 8; ++ct) {
                const int col = wcol + ct * 16 + r16;
                const float bv = bias[col];
                #pragma unroll
                for (int mt = 0; mt < 4; ++mt) {
                    const long rb = row0 + wrow + mt * 16 + quad * 4;
                    f32x4 a = acc[mt][ct];
                    #pragma unroll
                    for (int i = 0; i < 4; ++i) o[(rb + i) * DD + col] = a[i] + bv;
                }
            }
        }
    }
}

// ======================= small MFMA GEMM (128-row global path; split3, proven) =======================
struct GemmPtrs {
    const float* X;
    const ushort* W0; const ushort* W1; const ushort* W2;
    const float* b0; const float* b1; const float* b2;
    void* o0; void* o1; void* o2;
    int bf16mask;
};

__global__ __launch_bounds__(256, 2) void gemm_small(GemmPtrs p)
{
    __shared__ __align__(16) short As[2][128][40];
    __shared__ __align__(16) short Bsm[2][256][40];
    const int tid = threadIdx.x;
    const int w = tid >> 6, lane = tid & 63;
    const int quad = lane >> 4, r16 = lane & 15;
    const long row0 = (long)blockIdx.x * 128;
    const int mat = blockIdx.y;
    const ushort* W = (mat == 0) ? p.W0 : (mat == 1 ? p.W1 : p.W2);
    const float* bias = (mat == 0) ? p.b0 : (mat == 1 ? p.b1 : p.b2);
    void* out = (mat == 0) ? p.o0 : (mat == 1 ? p.o1 : p.o2);
    const int isbf = (p.bf16mask >> mat) & 1;
    const int wrow = (w & 1) * 64;
    const int wcol = (w >> 1) * 128;

    f32x4 acc[4][8];
    #pragma unroll
    for (int rt = 0; rt < 4; ++rt)
        #pragma unroll
        for (int ct = 0; ct < 8; ++ct)
            acc[rt][ct] = (f32x4){0.f, 0.f, 0.f, 0.f};

    const int arow = tid >> 1;
    const int kb = (tid & 1) << 4;
    const float* abase = p.X + (row0 + arow) * DD + kb;
    const short* wb = (const short*)W + tid * DD;

    for (int kc = 0; kc < 8; ++kc) {
        __syncthreads();
        {
            const float* src = abase + kc * 32;
            #pragma unroll
            for (int gx = 0; gx < 2; ++gx) {
                float4 x0 = *(const float4*)(src + gx * 8);
                float4 x1 = *(const float4*)(src + gx * 8 + 4);
                float xs[8] = {x0.x, x0.y, x0.z, x0.w, x1.x, x1.y, x1.z, x1.w};
                short h[8], l[8];
                #pragma unroll
                for (int i = 0; i < 8; ++i) split2(xs[i], h[i], l[i]);
                *(short8*)&As[0][arow][kb + gx * 8] = (short8){h[0],h[1],h[2],h[3],h[4],h[5],h[6],h[7]};
                *(short8*)&As[1][arow][kb + gx * 8] = (short8){l[0],l[1],l[2],l[3],l[4],l[5],l[6],l[7]};
            }
        }
        {
            const short* srcH = wb + kc * 32;
            const short* srcL = srcH + 65536;
            #pragma unroll
            for (int gx = 0; gx < 4; ++gx) {
                *(short8*)&Bsm[0][tid][gx * 8] = *(const short8*)(srcH + gx * 8);
                *(short8*)&Bsm[1][tid][gx * 8] = *(const short8*)(srcL + gx * 8);
            }
        }
        __syncthreads();
        short8 af[4][2];
        #pragma unroll
        for (int rt = 0; rt < 4; ++rt) {
            const int rr = wrow + rt * 16 + r16;
            af[rt][0] = *(const short8*)&As[0][rr][quad * 8];
            af[rt][1] = *(const short8*)&As[1][rr][quad * 8];
        }
        #pragma unroll
        for (int ct = 0; ct < 8; ++ct) {
            const int cc = wcol + ct * 16 + r16;
            short8 bh = *(const short8*)&Bsm[0][cc][quad * 8];
            short8 bl = *(const short8*)&Bsm[1][cc][quad * 8];
            #pragma unroll
            for (int rt = 0; rt < 4; ++rt) {
                acc[rt][ct] = __builtin_amdgcn_mfma_f32_16x16x32_bf16(af[rt][0], bh, acc[rt][ct], 0, 0, 0);
                acc[rt][ct] = __builtin_amdgcn_mfma_f32_16x16x32_bf16(af[rt][0], bl, acc[rt][ct], 0, 0, 0);
                acc[rt][ct] = __builtin_amdgcn_mfma_f32_16x16x32_bf16(af[rt][1], bh, acc[rt][ct], 0, 0, 0);
            }
        }
    }
    #pragma unroll
    for (int ct = 0; ct < 8; ++ct) {
        const int col = wcol + ct * 16 + r16;
        const float bv = bias[col];
        #pragma unroll
        for (int rt = 0; rt < 4; ++rt) {
            const long rb = row0 + wrow + rt * 16 + quad * 4;
            f32x4 a = acc[rt][ct];
            if (isbf) {
                ushort* o = (ushort*)out;
                #pragma unroll
                for (int i = 0; i < 4; ++i) o[(rb + i) * DD + col] = f2b(a[i] + bv);
            } else {
                float* o = (float*)out;
                #pragma unroll
                for (int i = 0; i < 4; ++i) o[(rb + i) * DD + col] = a[i] + bv;
            }
        }
    }
}

// ======================= banded attention: MFMA scores + MFMA PV (P hi/lo in LDS) =======================
// grid (cseq, 8 row-tiles, 8 heads), 64 threads (one wave). K/V scrambled bf16, Q fp32.
__global__ __launch_bounds__(64) void attn_mfma(const float* __restrict__ Q, const ushort* __restrict__ K,
                                                const ushort* __restrict__ V, float* __restrict__ O,
                                                float* __restrict__ part)
{
    __shared__ __align__(16) ushort Kt[96][40];     // [j][d] row-major
    __shared__ __align__(16) ushort VtT[32][120];   // [d][j] transposed, zero-padded j>=ktrows
    __shared__ __align__(16) ushort Pa[2][32][72];  // [hilo][i_loc][jr], zeros at jr>=48
    const int lane = threadIdx.x;
    const int quad = lane >> 4, r16 = lane & 15;
    const int t0 = blockIdx.y * 64;
    const int h = blockIdx.z;
    const long sbase = (long)blockIdx.x * 512;
    const int ktrows = (512 - t0) < 96 ? (512 - t0) : 96;

    // ---- stage K (row-major) and V^T from scrambled global ----
    #pragma unroll
    for (int it = 0; it < 12; ++it) {
        int u = lane + it * 64;                 // 768 = 24 row-quads x 32 cols
        int d = u & 31, r = (u >> 5) * 4;
        ushort4 kv = make_ushort4(0,0,0,0), vv = make_ushort4(0,0,0,0);
        if (r < ktrows) {
            size_t addr = scramble4((int)sbase + t0 + r, h * 32 + d);
            kv = *(const ushort4*)&K[addr];
            vv = *(const ushort4*)&V[addr];
        }
        Kt[r+0][d] = kv.x; Kt[r+1][d] = kv.y; Kt[r+2][d] = kv.z; Kt[r+3][d] = kv.w;
        *(ushort4*)&VtT[d][r] = vv;             // 4 consecutive j -> b64 (scrambled = col-of-4)
    }
    // zero-fill VtT cols 96..119 and Pa jr 48..63
    #pragma unroll
    for (int it = 0; it < 12; ++it) {
        int u = lane + it * 64;                 // 768
        int d = u / 24, j = 96 + (u % 24);
        VtT[d][j] = 0;
    }
    #pragma unroll
    for (int it = 0; it < 4; ++it) {
        int u = lane + it * 64;                 // 256 units of 4 ushorts
        int hl = u >> 7, i = (u >> 2) & 31, jq = (u & 3) * 4;
        *(ushort4*)&Pa[hl][i][48 + jq] = make_ushort4(0,0,0,0);
    }
    __syncthreads();

    float sm = 0.f, ssum = 0.f;

    #pragma unroll
    for (int p = 0; p < 2; ++p) {
        if (p) __syncthreads();                 // protect Pa reuse across passes
        // ---- scores for i in [p*32, p*32+32): 2 row-tiles x 3 col-tiles -> Pa (hi/lo bf16) ----
        #pragma unroll
        for (int mt = 0; mt < 2; ++mt) {
            const int mta = p * 2 + mt;
            const int i0 = mta * 16;
            const float* qp = &Q[(sbase + t0 + i0 + r16) * DD + h * 32 + quad * 8];
            float4 q0 = *(const float4*)qp;
            float4 q1 = *(const float4*)(qp + 4);
            float qs[8] = {q0.x, q0.y, q0.z, q0.w, q1.x, q1.y, q1.z, q1.w};
            short qh[8], ql[8];
            #pragma unroll
            for (int j = 0; j < 8; ++j) split2(qs[j], qh[j], ql[j]);
            short8 ah = {qh[0],qh[1],qh[2],qh[3],qh[4],qh[5],qh[6],qh[7]};
            short8 al = {ql[0],ql[1],ql[2],ql[3],ql[4],ql[5],ql[6],ql[7]};
            #pragma unroll
            for (int dnt = 0; dnt < 3; ++dnt) {
                const int nt = mta + dnt;
                short8 kb = *(const short8*)&Kt[nt * 16 + r16][quad * 8];
                f32x4 acc = (f32x4){0.f, 0.f, 0.f, 0.f};
                acc = __builtin_amdgcn_mfma_f32_16x16x32_bf16(ah, kb, acc, 0, 0, 0);
                acc = __builtin_amdgcn_mfma_f32_16x16x32_bf16(al, kb, acc, 0, 0, 0);
                const int j_loc = nt * 16 + r16;
                const int jr = dnt * 16 + r16;
                #pragma unroll
                for (int e = 0; e < 4; ++e) {
                    int iabs = i0 + quad * 4 + e;
                    int delta = j_loc - iabs;
                    bool valid = (delta >= 0) && (delta < 32) && (j_loc < ktrows);
                    float pv = valid ? acc[e] * __expf(-(float)delta) : 0.f;
                    short ph, pl;
                    split2(pv, ph, pl);
                    int il = mt * 16 + quad * 4 + e;
                    Pa[0][il][jr] = (ushort)ph;
                    Pa[1][il][jr] = (ushort)pl;
                }
            }
        }
        __syncthreads();
        // ---- PV via MFMA: O[i][d] = sum_j P[i][j] V[j][d] ----
        #pragma unroll
        for (int mt = 0; mt < 2; ++mt) {
            const int mta = p * 2 + mt;
            f32x4 oacc[2] = {(f32x4){0.f,0.f,0.f,0.f}, (f32x4){0.f,0.f,0.f,0.f}};
            #pragma unroll
            for (int kc = 0; kc < 2; ++kc) {
                short8 pah = *(const short8*)&Pa[0][mt * 16 + r16][kc * 32 + quad * 8];
                short8 pal = *(const short8*)&Pa[1][mt * 16 + r16][kc * 32 + quad * 8];
                #pragma unroll
                for (int dt = 0; dt < 2; ++dt) {
                    short8 vb = *(const short8*)&VtT[dt * 16 + r16][mta * 16 + kc * 32 + quad * 8];
                    oacc[dt] = __builtin_amdgcn_mfma_f32_16x16x32_bf16(pah, vb, oacc[dt], 0, 0, 0);
                    oacc[dt] = __builtin_amdgcn_mfma_f32_16x16x32_bf16(pal, vb, oacc[dt], 0, 0, 0);
                }
            }
            // C layout: col = d (r16), row = i (quad*4+e)
            #pragma unroll
            for (int dt = 0; dt < 2; ++dt) {
                #pragma unroll
                for (int e = 0; e < 4; ++e) {
                    long ir = sbase + t0 + p * 32 + mt * 16 + quad * 4 + e;
                    float val = oacc[dt][e];
                    O[ir * DD + h * 32 + dt * 16 + r16] = val;
                    sm += val; ssum += val * val;
                }
            }
        }
    }
    // ---- fused GN partial stats ----
    #pragma unroll
    for (int off = 32; off > 0; off >>= 1) {
        sm   += __shfl_down(sm, off, 64);
        ssum += __shfl_down(ssum, off, 64);
    }
    if (lane == 0) {
        atomicAdd(&part[2 * blockIdx.x], sm);
        atomicAdd(&part[2 * blockIdx.x + 1], ssum);
    }
}

// ======================= small dense attention (N=32), row-major bf16 K/V =======================
__global__ __launch_bounds__(64) void small_attn(const float* __restrict__ Q, const ushort* __restrict__ K,
                                                 const ushort* __restrict__ V, float* __restrict__ O)
{
    int b = blockIdx.x >> 3, h = blockIdx.x & 7;
    int i = threadIdx.x;
    if (i >= 32) return;
    long base = (long)b * 32 * DD + h * 32;
    float qr[32], o[32];
    #pragma unroll
    for (int d4 = 0; d4 < 8; ++d4) {
        float4 t = *(const float4*)&Q[base + (long)i * DD + d4 * 4];
        qr[d4*4+0] = t.x; qr[d4*4+1] = t.y; qr[d4*4+2] = t.z; qr[d4*4+3] = t.w;
    }
    #pragma unroll
    for (int d = 0; d < 32; ++d) o[d] = 0.f;
    for (int j = i; j < 32; ++j) {
        float s = 0.f;
        #pragma unroll
        for (int d4 = 0; d4 < 8; ++d4) {
            ushort4 kv = *(const ushort4*)&K[base + (long)j * DD + d4 * 4];
            s += qr[d4*4+0]*b2f(kv.x) + qr[d4*4+1]*b2f(kv.y) + qr[d4*4+2]*b2f(kv.z) + qr[d4*4+3]*b2f(kv.w);
        }
        s *= __expf(-(float)(j - i));
        #pragma unroll
        for (int d4 = 0; d4 < 8; ++d4) {
            ushort4 vv = *(const ushort4*)&V[base + (long)j * DD + d4 * 4];
            o[d4*4+0] += s*b2f(vv.x); o[d4*4+1] += s*b2f(vv.y); o[d4*4+2] += s*b2f(vv.z); o[d4*4+3] += s*b2f(vv.w);
        }
    }
    #pragma unroll
    for (int d4 = 0; d4 < 8; ++d4)
        *(float4*)&O[base + (long)i * DD + d4 * 4] = make_float4(o[d4*4+0], o[d4*4+1], o[d4*4+2], o[d4*4+3]);
}

// ======================= GN helpers =======================
__global__ __launch_bounds__(256) void gnzero(float* __restrict__ part)
{
    part[threadIdx.x] = 0.f;
}

__global__ __launch_bounds__(256) void gn_stats(const float* __restrict__ buf, float2* __restrict__ part, int rpb)
{
    const int s = blockIdx.x;
    const long base = (long)s * rpb * DD;
    const float4* p = (const float4*)(buf + base);
    const int nf4 = rpb * 64;
    float sm = 0.f, ss = 0.f;
    for (int i = threadIdx.x; i < nf4; i += 256) {
        float4 v = p[i];
        sm += v.x + v.y + v.z + v.w;
        ss += v.x*v.x + v.y*v.y + v.z*v.z + v.w*v.w;
    }
    #pragma unroll
    for (int off = 32; off > 0; off >>= 1) {
        sm += __shfl_down(sm, off, 64);
        ss += __shfl_down(ss, off, 64);
    }
    __shared__ float rs[4], rss[4];
    if ((threadIdx.x & 63) == 0) { rs[threadIdx.x >> 6] = sm; rss[threadIdx.x >> 6] = ss; }
    __syncthreads();
    if (threadIdx.x == 0)
        part[s] = make_float2(rs[0]+rs[1]+rs[2]+rs[3], rss[0]+rss[1]+rss[2]+rss[3]);
}

__global__ __launch_bounds__(256) void gn_final(float* __restrict__ part, float2* __restrict__ stats,
                                                int ng, float invN)
{
    int t = threadIdx.x;
    if (t < ng) {
        float sm = part[2*t], ss = part[2*t+1];
        float mean = sm * invN;
        float var = ss * invN - mean * mean;
        stats[t] = make_float2(mean, rsqrtf(var + 1e-5f));
        part[2*t] = 0.f; part[2*t+1] = 0.f;
    }
}

__global__ __launch_bounds__(256) void gn_apply(float* __restrict__ buf, const float2* __restrict__ stats,
                                                const float* __restrict__ w, const float* __restrict__ b, int shift)
{
    long i = (long)blockIdx.x * 256 + threadIdx.x;
    long e = i * 4;
    int seq = (int)(e >> shift);
    int d0 = (int)(e & 255);
    float2 st = stats[seq];
    float4 v = ((const float4*)buf)[i];
    float4 wv = *(const float4*)&w[d0];
    float4 bv = *(const float4*)&b[d0];
    v.x = (v.x - st.x) * st.y * wv.x + bv.x;
    v.y = (v.y - st.x) * st.y * wv.y + bv.y;
    v.z = (v.z - st.x) * st.y * wv.z + bv.z;
    v.w = (v.w - st.x) * st.y * wv.w + bv.w;
    ((float4*)buf)[i] = v;
}

// ======================= softmax-pool =======================
// big path: scrambled bf16 gate pre-activations + raw X + fused GN
__global__ __launch_bounds__(256) void pool_partial_big(const ushort* __restrict__ AW, const ushort* __restrict__ AU,
                                                        const float* __restrict__ X, const float2* __restrict__ stats,
                                                        const float* __restrict__ gnw, const float* __restrict__ gnb,
                                                        const float* __restrict__ g,
                                                        float* __restrict__ part, int rpb)
{
    const int s = blockIdx.x, ch = blockIdx.y, NC = gridDim.y, d = threadIdx.x;
    const long rowbase = ((long)s * NC + ch) * rpb;
    const float g0s = g[0];
    const float2 st = stats[s];
    const float wd = gnw[d], bd = gnb[d];
    float l = 0.f, acc = 0.f;
    for (int jj = 0; jj < rpb; jj += 4) {
        size_t addr = scramble4((int)rowbase + jj, d);
        ushort4 awv = *(const ushort4*)&AW[addr];
        ushort4 auv = *(const ushort4*)&AU[addr];
        ushort aws[4] = {awv.x, awv.y, awv.z, awv.w};
        ushort aus[4] = {auv.x, auv.y, auv.z, auv.w};
        #pragma unroll
        for (int i = 0; i < 4; ++i) {
            long idx = (rowbase + jj + i) * DD + d;
            float aw = b2f(aws[i]);
            float au = b2f(aus[i]);
            float x = (X[idx] - st.x) * st.y * wd + bd;
            float a = g0s * tanhf(aw) * (1.f / (1.f + __expf(-au)));
            float e = __expf(a);
            l += e; acc += e * x;
        }
    }
    long pbase = (long)(s * NC + ch) * 512;
    part[pbase + d] = l;
    part[pbase + 256 + d] = acc;
}

__global__ __launch_bounds__(256) void pool_partial_small(const float* __restrict__ AW, const float* __restrict__ AU,
                                                          const float* __restrict__ X, const float* __restrict__ g,
                                                          float* __restrict__ part, int rpb)
{
    const int s = blockIdx.x, d = threadIdx.x;
    const long rowbase = (long)s * rpb;
    const float g0 = g[0];
    float l = 0.f, acc = 0.f;
    for (int j = 0; j < rpb; ++j) {
        long idx = (rowbase + j) * DD + d;
        float a = g0 * tanhf(AW[idx]) * (1.f / (1.f + __expf(-AU[idx])));
        float e = __expf(a);
        l += e; acc += e * X[idx];
    }
    long pbase = (long)s * 512;
    part[pbase + d] = l;
    part[pbase + 256 + d] = acc;
}

__global__ __launch_bounds__(256) void pool_final(const float* __restrict__ part, float* __restrict__ out, int NC)
{
    const int s = blockIdx.x, d = threadIdx.x;
    float l = 0.f, acc = 0.f;
    for (int c = 0; c < NC; ++c) {
        long pbase = (long)(s * NC + c) * 512;
        l += part[pbase + d];
        acc += part[pbase + 256 + d];
    }
    out[(long)s * DD + d] = acc / l;
}

// ======================= BatchNorm + classifier =======================
__global__ __launch_bounds__(256) void bn_cls(const float* __restrict__ emb, const float* __restrict__ bn_w,
                                              const float* __restrict__ bn_b, const float* __restrict__ cls_W,
                                              const float* __restrict__ cls_b, float* __restrict__ out)
{
    int d = threadIdx.x;
    float e0 = emb[d], e1 = emb[256 + d], e2 = emb[512 + d], e3 = emb[768 + d];
    float mu = 0.25f * (e0 + e1 + e2 + e3);
    float v0 = e0 - mu, v1 = e1 - mu, v2 = e2 - mu, v3 = e3 - mu;
    float var = 0.25f * (v0*v0 + v1*v1 + v2*v2 + v3*v3);
    float rs = rsqrtf(var + 1e-5f);
    float w = bn_w[d], bb = bn_b[d];
    float z0 = v0*rs*w + bb, z1 = v1*rs*w + bb, z2 = v2*rs*w + bb, z3 = v3*rs*w + bb;
    float w0 = cls_W[d], w1 = cls_W[256 + d];
    __shared__ float red[8][256];
    red[0][d] = z0*w0; red[1][d] = z0*w1;
    red[2][d] = z1*w0; red[3][d] = z1*w1;
    red[4][d] = z2*w0; red[5][d] = z2*w1;
    red[6][d] = z3*w0; red[7][d] = z3*w1;
    __syncthreads();
    for (int off = 128; off > 0; off >>= 1) {
        if (d < off) {
            #pragma unroll
            for (int m = 0; m < 8; ++m) red[m][d] += red[m][d + off];
        }
        __syncthreads();
    }
    if (d < 8) out[d] = red[d][0] + cls_b[d & 1];
}

// ======================= host =======================
extern "C" void kernel_launch(void* const* d_in, const int* in_sizes, int n_in,
                              void* d_out, int out_size, void* d_ws, size_t ws_size,
                              hipStream_t stream)
{
    (void)in_sizes; (void)n_in; (void)out_size;
#define F(i) ((const float*)d_in[i])
    const float* bags = F(0);

    const size_t smallF = 1600000;
    int nch = 1;
    while (nch < 128) {
        size_t bigF_ = ((size_t)(128 / nch)) * 512 * 256;
        if ((3 * bigF_ + smallF) * 4 <= ws_size) break;
        nch <<= 1;
    }
    const int cseq = 128 / nch;
    const size_t crows = (size_t)cseq * 512;
    const size_t bigF = crows * 256;

    float* Xb  = (float*)d_ws;                 // attn output / gemm input (raw fp32)
    float* Qb  = Xb + bigF;                    // Q fp32
    float* KVb = Xb + 2 * bigF;                // K,V scrambled bf16 halves; later AW,AU
    ushort* Kb = (ushort*)KVb;
    ushort* Vb = Kb + crows * 256;
    float* sm = Xb + 3 * bigF;
    ushort* Wbig = (ushort*)sm;                // 8 mats x 65536 shorts (frag order, bf16)
    ushort* Wsm  = Wbig + 8 * 65536;           // 5 mats x 131072 shorts (hi/lo row-major)
    float* after = sm + 262144 + 327680;
    float* local_ = after;                     // 128*256
    float* gq   = local_ + 32768;
    float* gkv  = gq + 32768;
    ushort* gkb = (ushort*)gkv;
    ushort* gvb = gkb + 32768;
    float* go   = gkv + 32768;
    float* AWg  = go + 32768;
    float* AUg  = AWg + 32768;
    float* embb = AUg + 32768;                 // 1024
    float* gnpart = embb + 1024;               // 256 floats
    float2* gnstats = (float2*)(gnpart + 256); // 128 x float2
    float* ppart = gnpart + 512;               // [1024][512] max

    // --- weight conversion ---
    WPtrs8 wb8; const int bigidx[8] = {1, 3, 5, 9, 11, 13, 25, 27};
    for (int i = 0; i < 8; ++i) wb8.w[i] = F(bigidx[i]);
    wcvt_frag<<<256, 256, 0, stream>>>(wb8, Wbig);
    WPtrs5 ws5; const int smidx[5] = {17, 19, 21, 30, 32};
    for (int i = 0; i < 5; ++i) ws5.w[i] = F(smidx[i]);
    wcvt_old<<<320, 256, 0, stream>>>(ws5, Wsm);
    gnzero<<<1, 256, 0, stream>>>(gnpart);

    dim3 blk(256);
    const int gx = (int)(crows / 128);
    const float invBig = 1.f / 131072.f;

    for (int c = 0; c < nch; ++c) {
        const float* xin = bags + (size_t)c * bigF;
        // retention 1 (Q fp32 row-major, K/V scrambled bf16)
        GemmFused g1 = {xin, nullptr, nullptr, nullptr, Wbig,
                        F(2), F(4), F(6), Qb, Kb, Vb, 0b110, 3};
        gemm_fused<<<gx, blk, 0, stream>>>(g1);
        attn_mfma<<<dim3(cseq, 8, 8), 64, 0, stream>>>(Qb, Kb, Vb, Xb, gnpart);
        gn_final<<<1, blk, 0, stream>>>(gnpart, gnstats, cseq, invBig);
        // retention 2 (GN of layer1 fused into A-staging)
        GemmFused g2 = {Xb, gnstats, F(7), F(8), Wbig + 3 * 65536,
                        F(10), F(12), F(14), Qb, Kb, Vb, 0b110, 3};
        gemm_fused<<<gx, blk, 0, stream>>>(g2);
        attn_mfma<<<dim3(cseq, 8, 8), 64, 0, stream>>>(Qb, Kb, Vb, Xb, gnpart);
        gn_final<<<1, blk, 0, stream>>>(gnpart, gnstats, cseq, invBig);
        // local pool (GN of layer2 fused; gates out scrambled bf16)
        GemmFused gp = {Xb, gnstats, F(15), F(16), Wbig + 6 * 65536,
                        F(26), F(28), nullptr, Kb, Vb, nullptr, 0b11, 2};
        gemm_fused<<<gx, blk, 0, stream>>>(gp);
        pool_partial_big<<<dim3(cseq, 8), blk, 0, stream>>>(Kb, Vb, Xb, gnstats, F(15), F(16), F(29), ppart, 64);
        pool_final<<<cseq, blk, 0, stream>>>(ppart, local_ + (size_t)c * cseq * 256, 8);
    }

    // global retention on local [4 x 32 x 256] = 128 rows
    GemmPtrs gg = {local_, Wsm, Wsm + 131072, Wsm + 2 * 131072,
                   F(18), F(20), F(22), gq, gkb, gvb, 0b110};
    gemm_small<<<dim3(1, 3), blk, 0, stream>>>(gg);
    small_attn<<<32, 64, 0, stream>>>(gq, gkb, gvb, go);
    gn_stats<<<4, blk, 0, stream>>>(go, (float2*)gnpart, 32);
    gn_final<<<1, blk, 0, stream>>>(gnpart, gnstats, 4, 1.f / 8192.f);
    gn_apply<<<32, blk, 0, stream>>>(go, gnstats, F(23), F(24), 13);

    GemmPtrs gpg = {go, Wsm + 3 * 131072, Wsm + 4 * 131072, nullptr,
                    F(31), F(33), nullptr, AWg, AUg, nullptr, 0};
    gemm_small<<<dim3(1, 2), blk, 0, stream>>>(gpg);
    pool_partial_small<<<4, blk, 0, stream>>>(AWg, AUg, go, F(34), ppart, 32);
    pool_final<<<4, blk, 0, stream>>>(ppart, embb, 1);

    bn_cls<<<1, blk, 0, stream>>>(embb, F(35), F(36), F(37), F(38), (float*)d_out);
#undef F
}